// Round 19
// baseline (313.963 us; speedup 1.0000x reference)
//
#include <hip/hip_runtime.h>
#include <math.h>

#define NB 128
#define NT 8
#define NJ 22
#define NF 128
#define NH 8
#define NDH 64
#define NS 66     // 3*NJ
#define NW 6      // NT-2
#define NOUT 512
#define NHD 512   // NH*NDH
#define NEGV -9e15f
#define HPB 4
#define RTOT 22528   // B*T*J

typedef short bf16x8 __attribute__((ext_vector_type(8)));
typedef float f32x4  __attribute__((ext_vector_type(4)));
typedef unsigned int uint4v __attribute__((ext_vector_type(4)));

// ---- LDS regions for ultra-fallback attn kernel (ushort offsets) ----
#define XWPH 0
#define XWPL 8448
#define QH   16896
#define QL   21648
#define KH   26400
#define KL   31152
#define OTF_U 26400
#define VT_F 36128
#define LDS_USHORT 40736

// ---- workspace layout (ushort offsets) ----
#define WQH 0          // prepped W^T hi/lo: [512][128]
#define WQL 65536
#define WKH 131072
#define WKL 196608
#define WVT 262144
#define WFH 327680     // WftT hi [512][512]
#define WFL 589824
#define PEU 851968     // PE fp32 table [176][128]
#define GQP 897024     // q packed hi|lo<<16: uint32 [8][22528][64]
#define GKP 23965696   // k packed
#define GVR 47034368   // v row-major ushort [8][128][176][64]
#define HS  1441792    // per-head plane stride in ELEMENTS ([22528][64])
#define VBS 11264      // 176*64
#define WS_FULL_BYTES 117137408ULL

__device__ __forceinline__ unsigned short bfc(float f) {
    union { float f; unsigned u; } v; v.f = f;
    unsigned r = v.u + 0x7FFFu + ((v.u >> 16) & 1u);
    return (unsigned short)(r >> 16);
}
__device__ __forceinline__ float b2f(unsigned short h) {
    union { unsigned u; float f; } v; v.u = ((unsigned)h) << 16;
    return v.f;
}
// unpack 8 dwords (hi|lo<<16) -> hi-bf16x8, lo-bf16x8
__device__ __forceinline__ void unpack_hl(const unsigned int* p, bf16x8* hi, bf16x8* lo) {
    uint4v a = *(const uint4v*)p;
    uint4v b = *(const uint4v*)(p + 4);
    union { unsigned int u[4]; bf16x8 v; } H, L;
    H.u[0] = __builtin_amdgcn_perm(a[1], a[0], 0x05040100u);
    H.u[1] = __builtin_amdgcn_perm(a[3], a[2], 0x05040100u);
    H.u[2] = __builtin_amdgcn_perm(b[1], b[0], 0x05040100u);
    H.u[3] = __builtin_amdgcn_perm(b[3], b[2], 0x05040100u);
    L.u[0] = __builtin_amdgcn_perm(a[1], a[0], 0x07060302u);
    L.u[1] = __builtin_amdgcn_perm(a[3], a[2], 0x07060302u);
    L.u[2] = __builtin_amdgcn_perm(b[1], b[0], 0x07060302u);
    L.u[3] = __builtin_amdgcn_perm(b[3], b[2], 0x07060302u);
    *hi = H.v; *lo = L.v;
}

// ---------------------------------------------------------------------------
// prep: W panels (transpose + hi/lo split) + PE fp32 table
// ---------------------------------------------------------------------------
__global__ __launch_bounds__(256) void prep_kernel(
    const float* __restrict__ Wq, const float* __restrict__ Wk,
    const float* __restrict__ Wv, const float* __restrict__ Wft,
    unsigned short* __restrict__ ws)
{
    int idx = blockIdx.x * 256 + threadIdx.x;
    if (idx < 196608) {
        int m = idx >> 16;
        int r = idx & 65535;
        int col = r >> 7, f = r & 127;
        const float* W = (m == 0) ? Wq : ((m == 1) ? Wk : Wv);
        float v = W[f * NHD + col];
        unsigned short h = bfc(v);
        if (m == 0)      { ws[WQH + r] = h; ws[WQL + r] = bfc(v - b2f(h)); }
        else if (m == 1) { ws[WKH + r] = h; ws[WKL + r] = bfc(v - b2f(h)); }
        else             { ws[WVT + r] = h; }
    } else if (idx < 458752) {
        int r = idx - 196608;
        int col = r >> 9, f = r & 511;
        float v = Wft[f * NOUT + col];
        unsigned short h = bfc(v);
        ws[WFH + r] = h;
        ws[WFL + r] = bfc(v - b2f(h));
    } else {
        int r = idx - 458752;          // [tj][f]
        int tj = r >> 7, f = r & 127;
        int t = tj / 22, j = tj - t * 22;
        const float cdiv = -0.0719557841560639f;
        float dv = __expf(cdiv * (float)(f & ~1));
        float pe = ((f & 1) == 0) ? (__sinf((float)j * dv) + __sinf((float)t * dv))
                                  : (__cosf((float)j * dv) + __cosf((float)t * dv));
        ((float*)(ws + PEU))[r] = pe;
    }
}

// ---------------------------------------------------------------------------
// Phase 1: QKV projection GEMM. M=64/block, XCD-aligned. grid 1056.
// (256,3): 3 blocks/CU — qkv has no private per-wave read set, so extra
// resident waves hide latency without L2 thrash (unlike attn, R12).
// ---------------------------------------------------------------------------
__global__ __launch_bounds__(256, 3) void qkv_kernel(
    const float* __restrict__ x,
    const float* __restrict__ bq, const float* __restrict__ bk,
    const float* __restrict__ bv,
    const unsigned short* __restrict__ ws,
    unsigned short* __restrict__ wso)
{
    __shared__ __align__(16) unsigned short ah[64 * 136];
    __shared__ __align__(16) unsigned short al[64 * 136];
    const int tid = threadIdx.x, lane = tid & 63, wv = tid >> 6;
    const int l15 = lane & 15, lg = lane >> 4;
    // XCD-aligned work mapping: t8 = XCD, 132 blocks each (44 row-blocks x 3 mats)
    const int t8 = blockIdx.x & 7;
    const int s8 = blockIdx.x >> 3;
    const int mat  = s8 % 3;
    const int row0 = (44 * t8 + s8 / 3) * 64;
    const float* PEf = (const float*)(ws + PEU);

    const int tjbase = row0 % 176;
    for (int idx = tid; idx < 64 * 32; idx += 256) {
        int rr = idx >> 5, f4 = (idx & 31) * 4;
        int tj = tjbase + rr; if (tj >= 176) tj -= 176;
        f32x4 xv = *(const f32x4*)&x[(row0 + rr) * NF + f4];
        f32x4 pe = *(const f32x4*)&PEf[tj * 128 + f4];
#pragma unroll
        for (int i = 0; i < 4; ++i) {
            float val = xv[i] + pe[i];
            unsigned short hs = bfc(val);
            ah[rr * 136 + f4 + i] = hs;
            al[rr * 136 + f4 + i] = bfc(val - b2f(hs));
        }
    }
    __syncthreads();

    const unsigned short* WH = (mat == 0) ? (ws + WQH) : ((mat == 1) ? (ws + WKH) : (ws + WVT));
    const unsigned short* WL = (mat == 0) ? (ws + WQL) : (ws + WKL);
    const float* bias = (mat == 0) ? bq : ((mat == 1) ? bk : bv);

    f32x4 acc[4][8];
#pragma unroll
    for (int m = 0; m < 4; ++m)
#pragma unroll
        for (int g = 0; g < 8; ++g) acc[m][g] = (f32x4){0, 0, 0, 0};

#pragma unroll
    for (int ka = 0; ka < 4; ++ka) {
        bf16x8 bhA[8], blA[8];
#pragma unroll
        for (int g = 0; g < 8; ++g) {
            int col = (wv * 8 + g) * 16 + l15;
            bhA[g] = *(const bf16x8*)&WH[col * 128 + ka * 32 + lg * 8];
        }
        if (mat < 2) {
#pragma unroll
            for (int g = 0; g < 8; ++g) {
                int col = (wv * 8 + g) * 16 + l15;
                blA[g] = *(const bf16x8*)&WL[col * 128 + ka * 32 + lg * 8];
            }
        }
        bf16x8 afh[4], afl[4];
#pragma unroll
        for (int m = 0; m < 4; ++m) {
            afh[m] = *(const bf16x8*)&ah[(m * 16 + l15) * 136 + ka * 32 + lg * 8];
            afl[m] = *(const bf16x8*)&al[(m * 16 + l15) * 136 + ka * 32 + lg * 8];
        }
#pragma unroll
        for (int g = 0; g < 8; ++g) {
#pragma unroll
            for (int m = 0; m < 4; ++m)
                acc[m][g] = __builtin_amdgcn_mfma_f32_16x16x32_bf16(afh[m], bhA[g], acc[m][g], 0, 0, 0);
            if (mat < 2) {
#pragma unroll
                for (int m = 0; m < 4; ++m) {
                    acc[m][g] = __builtin_amdgcn_mfma_f32_16x16x32_bf16(afh[m], blA[g], acc[m][g], 0, 0, 0);
                    acc[m][g] = __builtin_amdgcn_mfma_f32_16x16x32_bf16(afl[m], bhA[g], acc[m][g], 0, 0, 0);
                }
            }
        }
    }

#pragma unroll
    for (int g = 0; g < 8; ++g) {
        int cg = wv * 8 + g;
        int colg = cg * 16 + l15;
        int h2 = cg >> 2;
        int c = (cg & 3) * 16 + l15;
        float bv_ = bias[colg];
        if (mat == 2) {
#pragma unroll
            for (int m = 0; m < 4; ++m)
#pragma unroll
                for (int r = 0; r < 4; ++r) {
                    int row = row0 + m * 16 + lg * 4 + r;
                    int bb = row / 176;
                    int tj = row - bb * 176;
                    wso[GVR + (size_t)(h2 * NB + bb) * VBS + tj * 64 + c] =
                        bfc(fmaxf(acc[m][g][r] + bv_, 0.f));
                }
        } else {
            unsigned int* OP = (unsigned int*)(wso + ((mat == 0) ? GQP : GKP)) + (size_t)h2 * HS;
            const float scale = (mat == 0) ? 0.125f : 1.0f;
#pragma unroll
            for (int m = 0; m < 4; ++m)
#pragma unroll
                for (int r = 0; r < 4; ++r) {
                    int row = row0 + m * 16 + lg * 4 + r;
                    float v = (acc[m][g][r] + bv_) * scale;
                    unsigned short h = bfc(v);
                    unsigned short l = bfc(v - b2f(h));
                    OP[row * 64 + c] = (unsigned int)h | ((unsigned int)l << 16);
                }
        }
    }
}

// ---------------------------------------------------------------------------
// Phase 2 (attn12): R18 champion, unchanged. grid 1536.
// ---------------------------------------------------------------------------
#define PWS7 4752

__global__ __launch_bounds__(256, 2) void attn_kernel12(
    const unsigned short* __restrict__ ws,
    const float* __restrict__ Wcls, const float* __restrict__ bcls,
    float* __restrict__ out)
{
    __shared__ __align__(16) unsigned short lds[4 * PWS7];   // 38016 B
    const int tid  = threadIdx.x;
    const int lane = tid & 63;
    const int wv   = tid >> 6;
    const int l15  = lane & 15;
    const int lg   = lane >> 4;
    const int nbid = ((blockIdx.x & 7) * 192) + (blockIdx.x >> 3);  // XCD swizzle
    const int gid  = nbid * 4 + wv;
    const int w = gid % 6;
    const int h = (gid / 6) & 7;
    const int b = gid / 48;
    const int rowbase = b * 176 + w * 22;
    unsigned short* P = lds + wv * PWS7;

    const unsigned int* qpb = (const unsigned int*)(ws + GQP) + (size_t)h * HS + rowbase * 64;
    const unsigned int* kpb = (const unsigned int*)(ws + GKP) + (size_t)h * HS + rowbase * 64;
    const unsigned short* vrb = ws + GVR + (size_t)(h * NB + b) * VBS + (w * 22) * 64;

    // ---- prefetch ALL of K (packed) -> registers, unpack to hi/lo ----
    bf16x8 kh_r[5][2], kl_r[5][2];
#pragma unroll
    for (int nt = 0; nt < 5; ++nt) {
        int colr = nt * 16 + l15; if (colr > 65) colr = 65;
#pragma unroll
        for (int ks = 0; ks < 2; ++ks)
            unpack_hl(&kpb[colr * 64 + ks * 32 + lg * 8], &kh_r[nt][ks], &kl_r[nt][ks]);
    }

    // ---- stage V (row-major) -> P region transposed [d][s] ----
#pragma unroll
    for (int it = 0; it < 8; ++it) {
        bf16x8 vvv = *(const bf16x8*)&vrb[lane * 64 + it * 8];   // s=lane
#pragma unroll
        for (int i = 0; i < 8; ++i) P[(it * 8 + i) * 72 + lane] = (unsigned short)vvv[i];
    }
    if (lane < 16) {
        int s2 = 64 + (lane & 1);
        int o2 = lane >> 1;
        bf16x8 vvv = *(const bf16x8*)&vrb[s2 * 64 + o2 * 8];
#pragma unroll
        for (int i = 0; i < 8; ++i) P[(o2 * 8 + i) * 72 + s2] = (unsigned short)vvv[i];
    }

    // ---- Wcls A-fragments (independent; executes in the V/K miss shadow) ----
    bf16x8 wfrag[2][2];
#pragma unroll
    for (int mt = 0; mt < 2; ++mt)
#pragma unroll
        for (int ks = 0; ks < 2; ++ks) {
            int j = mt * 16 + l15;
            bf16x8 t;
#pragma unroll
            for (int i = 0; i < 8; ++i) {
                int s = ks * 32 + lg * 8 + i;
                float v = (j < NJ) ? Wcls[s * NJ + j] : 0.f;
                t[i] = (short)bfc(v);
            }
            wfrag[mt][ks] = t;
        }

    asm volatile("s_waitcnt lgkmcnt(0)" ::: "memory");
    __builtin_amdgcn_sched_barrier(0);

    bf16x8 vreg[4][2];
    float v64r[4], v65r[4];
#pragma unroll
    for (int nt = 0; nt < 4; ++nt) {
        const int dn = nt * 16 + l15;
        vreg[nt][0] = *(const bf16x8*)&P[dn * 72 + lg * 8];
        vreg[nt][1] = *(const bf16x8*)&P[dn * 72 + 32 + lg * 8];
        unsigned int vv = *(const unsigned int*)&P[dn * 72 + 64];
        v64r[nt] = b2f((unsigned short)(vv & 0xffffu));
        v65r[nt] = b2f((unsigned short)(vv >> 16));
    }
    asm volatile("s_waitcnt lgkmcnt(0)" ::: "memory");
    __builtin_amdgcn_sched_barrier(0);

    // ---- scores + mask + threshold + softmax (shift = mv) -> P ----
#pragma unroll
    for (int mt = 0; mt < 5; ++mt) {
        int rowc = mt * 16 + l15; if (rowc > 65) rowc = 65;
        bf16x8 qh2[2], ql2[2];
#pragma unroll
        for (int ks = 0; ks < 2; ++ks)
            unpack_hl(&qpb[rowc * 64 + ks * 32 + lg * 8], &qh2[ks], &ql2[ks]);
        f32x4 c[5];
#pragma unroll
        for (int nt = 0; nt < 5; ++nt) {
            f32x4 acc = {0, 0, 0, 0};
#pragma unroll
            for (int ks = 0; ks < 2; ++ks) {
                acc = __builtin_amdgcn_mfma_f32_16x16x32_bf16(qh2[ks], kh_r[nt][ks], acc, 0, 0, 0);
                acc = __builtin_amdgcn_mfma_f32_16x16x32_bf16(qh2[ks], kl_r[nt][ks], acc, 0, 0, 0);
                acc = __builtin_amdgcn_mfma_f32_16x16x32_bf16(ql2[ks], kh_r[nt][ks], acc, 0, 0, 0);
            }
            c[nt] = acc;
        }
#pragma unroll
        for (int r = 0; r < 4; ++r) {
            int srow = mt * 16 + lg * 4 + r;
            int fi = (srow >= 44) ? 2 : ((srow >= 22) ? 1 : 0);
            float sv[5];
            float mv = -INFINITY;
#pragma unroll
            for (int nt = 0; nt < 5; ++nt) {
                int j = nt * 16 + l15;
                int fj = (j >= 44) ? 2 : ((j >= 22) ? 1 : 0);
                float s = c[nt][r];
                if ((fi == 0 && fj == 2) || (fi == 2 && fj == 0)) s = 0.f;
                sv[nt] = s;
                if (j < NS) mv = fmaxf(mv, s);
            }
#pragma unroll
            for (int off = 1; off < 16; off <<= 1) mv = fmaxf(mv, __shfl_xor(mv, off));
            float thr = mv * (1.f / 9.f);
            float pv5[5];
            float sum = 0.f;
#pragma unroll
            for (int nt = 0; nt < 5; ++nt) {
                int j = nt * 16 + l15;
                float e = (j < NS && fabsf(sv[nt]) > thr) ? sv[nt] : NEGV;
                float p = __expf(e - mv);
                pv5[nt] = p;
                sum += p;
            }
#pragma unroll
            for (int off = 1; off < 16; off <<= 1) sum += __shfl_xor(sum, off);
            float inv = 1.f / sum;
            if (srow < NS) {
#pragma unroll
                for (int nt = 0; nt < 5; ++nt) {
                    unsigned short ph = bfc(pv5[nt] * inv);
                    if (nt < 4)           P[srow * 72 + nt * 16 + l15] = ph;
                    else if (l15 < 2)     P[srow * 72 + 64 + l15]      = ph;
                }
            }
        }
    }
    asm volatile("s_waitcnt lgkmcnt(0)" ::: "memory");
    __builtin_amdgcn_sched_barrier(0);

    // ---- PV + in-register Wcls, per d-tile nt ----
#pragma unroll
    for (int nt = 0; nt < 4; ++nt) {
        const int dn = nt * 16 + l15;
        const float v64 = v64r[nt];
        const float v65 = v65r[nt];

        f32x4 o[5];
#pragma unroll
        for (int mt = 0; mt < 5; ++mt) {
            int rowc = mt * 16 + l15; if (rowc > 65) rowc = 65;
            f32x4 a = {0, 0, 0, 0};
#pragma unroll
            for (int ks = 0; ks < 2; ++ks) {
                bf16x8 pa = *(const bf16x8*)&P[rowc * 72 + ks * 32 + lg * 8];
                a = __builtin_amdgcn_mfma_f32_16x16x32_bf16(pa, vreg[nt][ks], a, 0, 0, 0);
            }
#pragma unroll
            for (int r = 0; r < 4; ++r) {
                int s2 = mt * 16 + lg * 4 + r;
                if (s2 < NS) {
                    float p64 = b2f(P[s2 * 72 + 64]);
                    float p65 = b2f(P[s2 * 72 + 65]);
                    a[r] += p64 * v64 + p65 * v65;
                }
            }
            o[mt] = a;
        }

        unsigned int pk0[4], pk1[4];
#pragma unroll
        for (int mt = 0; mt < 4; ++mt) {
            pk0[mt] = (unsigned int)bfc(o[mt][0]) | ((unsigned int)bfc(o[mt][1]) << 16);
            pk1[mt] = (unsigned int)bfc(o[mt][2]) | ((unsigned int)bfc(o[mt][3]) << 16);
        }
        const int L0 = l15 + 16 * ((lg & 1) * 2);
        const int L1 = L0 + 16;
        const bool hiSel = (lg >> 1) & 1;

        bf16x8 bfr[2];
#pragma unroll
        for (int ks2 = 0; ks2 < 2; ++ks2) {
            unsigned int s00 = __shfl((int)pk0[2 * ks2],     L0);
            unsigned int s01 = __shfl((int)pk1[2 * ks2],     L0);
            unsigned int s10 = __shfl((int)pk0[2 * ks2 + 1], L0);
            unsigned int s11 = __shfl((int)pk1[2 * ks2 + 1], L0);
            unsigned int t00 = __shfl((int)pk0[2 * ks2],     L1);
            unsigned int t01 = __shfl((int)pk1[2 * ks2],     L1);
            unsigned int t10 = __shfl((int)pk0[2 * ks2 + 1], L1);
            unsigned int t11 = __shfl((int)pk1[2 * ks2 + 1], L1);
            uint4v dw;
            dw[0] = hiSel ? s10 : s00;
            dw[1] = hiSel ? s11 : s01;
            dw[2] = hiSel ? t10 : t00;
            dw[3] = hiSel ? t11 : t01;
            union { uint4v u; bf16x8 b; } cv; cv.u = dw;
            bfr[ks2] = cv.b;
        }
        const float o64 = __shfl(o[4][0], l15);
        const float o65 = __shfl(o[4][1], l15);

        f32x4 C2[2];
#pragma unroll
        for (int jt = 0; jt < 2; ++jt) {
            f32x4 a = {0, 0, 0, 0};
#pragma unroll
            for (int ks2 = 0; ks2 < 2; ++ks2)
                a = __builtin_amdgcn_mfma_f32_16x16x32_bf16(wfrag[jt][ks2], bfr[ks2], a, 0, 0, 0);
            C2[jt] = a;
        }
#pragma unroll
        for (int jt = 0; jt < 2; ++jt) {
#pragma unroll
            for (int r = 0; r < 4; ++r) {
                int jj = jt * 16 + lg * 4 + r;
                if (jj < NJ) {
                    float res = C2[jt][r] + Wcls[64 * NJ + jj] * o64
                                          + Wcls[65 * NJ + jj] * o65 + bcls[jj];
                    out[((b * (NW * NJ) + w * NJ + jj) * NHD) + h * 64 + dn] = res;
                }
            }
        }
    }
}

// ---------------------------------------------------------------------------
// ft v4: M=32/block; 16-load B burst; XCD-aligned with attn's out writes.
// ---------------------------------------------------------------------------
__global__ __launch_bounds__(256, 2) void ft_ln4(
    const unsigned short* __restrict__ ws,
    const float* __restrict__ bft,
    const float* __restrict__ a2, const float* __restrict__ b2,
    float* __restrict__ out)
{
    __shared__ __align__(16) unsigned short sAH[32 * 536];
    __shared__ __align__(16) unsigned short sAL[32 * 536];
    __shared__ float red[2][4][32];
    const int tid = threadIdx.x, lane = tid & 63, wv = tid >> 6;
    const int l15 = lane & 15, lg = lane >> 4;
    const int nb = (blockIdx.x & 7) * 66 + (blockIdx.x >> 3);
    const int base = nb * (32 * NOUT);

    for (int idx = tid; idx < 32 * NOUT; idx += 256) {
        int r = idx >> 9, c = idx & 511;
        float v = out[base + idx];
        unsigned short h = bfc(v);
        sAH[r * 536 + c] = h;
        sAL[r * 536 + c] = bfc(v - b2f(h));
    }
    __syncthreads();

    f32x4 acc[2][8];
#pragma unroll
    for (int m = 0; m < 2; ++m)
#pragma unroll
        for (int g = 0; g < 8; ++g) acc[m][g] = (f32x4){0, 0, 0, 0};

    for (int ka = 0; ka < 16; ++ka) {
        bf16x8 bh[8], bl[8];
#pragma unroll
        for (int g = 0; g < 8; ++g) {
            int col = (wv * 8 + g) * 16 + l15;
            bh[g] = *(const bf16x8*)&ws[WFH + col * 512 + ka * 32 + lg * 8];
            bl[g] = *(const bf16x8*)&ws[WFL + col * 512 + ka * 32 + lg * 8];
        }
        bf16x8 afh[2], afl[2];
#pragma unroll
        for (int m = 0; m < 2; ++m) {
            afh[m] = *(const bf16x8*)&sAH[(m * 16 + l15) * 536 + ka * 32 + lg * 8];
            afl[m] = *(const bf16x8*)&sAL[(m * 16 + l15) * 536 + ka * 32 + lg * 8];
        }
#pragma unroll
        for (int g = 0; g < 8; ++g) {
#pragma unroll
            for (int m = 0; m < 2; ++m) {
                acc[m][g] = __builtin_amdgcn_mfma_f32_16x16x32_bf16(afh[m], bh[g], acc[m][g], 0, 0, 0);
                acc[m][g] = __builtin_amdgcn_mfma_f32_16x16x32_bf16(afh[m], bl[g], acc[m][g], 0, 0, 0);
                acc[m][g] = __builtin_amdgcn_mfma_f32_16x16x32_bf16(afl[m], bh[g], acc[m][g], 0, 0, 0);
            }
        }
    }

#pragma unroll
    for (int g = 0; g < 8; ++g) {
        int col = (wv * 8 + g) * 16 + l15;
        float bfv = bft[col];
#pragma unroll
        for (int m = 0; m < 2; ++m)
#pragma unroll
            for (int r = 0; r < 4; ++r)
                acc[m][g][r] = fmaxf(acc[m][g][r] + bfv, 0.f);
    }

    float ps[2][4], pq[2][4];
#pragma unroll
    for (int m = 0; m < 2; ++m)
#pragma unroll
        for (int r = 0; r < 4; ++r) {
            float s = 0.f, q = 0.f;
#pragma unroll
            for (int g = 0; g < 8; ++g) {
                s += acc[m][g][r];
                q = fmaf(acc[m][g][r], acc[m][g][r], q);
            }
            ps[m][r] = s; pq[m][r] = q;
        }
#pragma unroll
    for (int off = 1; off < 16; off <<= 1) {
#pragma unroll
        for (int m = 0; m < 2; ++m)
#pragma unroll
            for (int r = 0; r < 4; ++r) {
                ps[m][r] += __shfl_xor(ps[m][r], off);
                pq[m][r] += __shfl_xor(pq[m][r], off);
            }
    }
    if (l15 == 0) {
#pragma unroll
        for (int m = 0; m < 2; ++m)
#pragma unroll
            for (int r = 0; r < 4; ++r) {
                int row = m * 16 + lg * 4 + r;
                red[0][wv][row] = ps[m][r];
                red[1][wv][row] = pq[m][r];
            }
    }
    __syncthreads();

    float mean[2][4], inv[2][4];
#pragma unroll
    for (int m = 0; m < 2; ++m)
#pragma unroll
        for (int r = 0; r < 4; ++r) {
            int row = m * 16 + lg * 4 + r;
            float s = red[0][0][row] + red[0][1][row] + red[0][2][row] + red[0][3][row];
            float q = red[1][0][row] + red[1][1][row] + red[1][2][row] + red[1][3][row];
            float mn = s * (1.0f / 512.0f);
            float var = fmaxf((q - 512.0f * mn * mn) * (1.0f / 511.0f), 0.0f);
            mean[m][r] = mn;
            inv[m][r] = 1.0f / (sqrtf(var) + 1e-6f);
        }
#pragma unroll
    for (int g = 0; g < 8; ++g) {
        int col = (wv * 8 + g) * 16 + l15;
        float av2 = a2[col], bv2 = b2[col];
#pragma unroll
        for (int m = 0; m < 2; ++m)
#pragma unroll
            for (int r = 0; r < 4; ++r) {
                int row = m * 16 + lg * 4 + r;
                out[base + row * NOUT + col] = av2 * (acc[m][g][r] - mean[m][r]) * inv[m][r] + bv2;
            }
    }
}

// ===========================================================================
// Ultra fallback (no ws): self-contained attn + fp32 ft/LN (proven R3 path)
// ===========================================================================
__global__ __launch_bounds__(256) void attn_kernel(
    const float* __restrict__ x,
    const float* __restrict__ Wq, const float* __restrict__ bq,
    const float* __restrict__ Wk, const float* __restrict__ bk,
    const float* __restrict__ Wv, const float* __restrict__ bv,
    const float* __restrict__ Wcls, const float* __restrict__ bcls,
    float* __restrict__ out)
{
    __shared__ __align__(16) unsigned short lds[LDS_USHORT];
    float* OTf = (float*)&lds[OTF_U];

    const int tid  = threadIdx.x;
    const int lane = tid & 63;
    const int wv   = tid >> 6;
    const int l15  = lane & 15;
    const int lg   = lane >> 4;
    const int bid  = blockIdx.x;
    const int hb   = bid & 1;
    const int w    = (bid >> 1) % NW;
    const int b    = bid / (2 * NW);

    const float cdiv = -0.0719557841560639f;
    for (int idx = tid; idx < NS * NF; idx += 256) {
        int s = idx >> 7, f = idx & 127;
        int i = (s >= 44) ? 2 : ((s >= 22) ? 1 : 0);
        int j = s - i * NJ;
        int fr = w + i;
        float xv = x[((b * NT + fr) * NJ + j) * NF + f];
        float dv = __expf(cdiv * (float)(f & ~1));
        float pe = ((f & 1) == 0) ? (__sinf((float)j * dv) + __sinf((float)fr * dv))
                                  : (__cosf((float)j * dv) + __cosf((float)fr * dv));
        float val = xv + pe;
        unsigned short hs = bfc(val);
        int addr = s * 128 + ((((f >> 3) ^ (s & 15))) << 3) + (f & 7);
        lds[XWPH + addr] = hs;
        lds[XWPL + addr] = bfc(val - b2f(hs));
    }

    bf16x8 wfrag[2][2];
#pragma unroll
    for (int mt = 0; mt < 2; ++mt)
#pragma unroll
        for (int ks = 0; ks < 2; ++ks) {
            int j = mt * 16 + l15;
            bf16x8 t;
#pragma unroll
            for (int i = 0; i < 8; ++i) {
                int s = ks * 32 + lg * 8 + i;
                float v = (j < NJ) ? Wcls[s * NJ + j] : 0.f;
                t[i] = (short)bfc(v);
            }
            wfrag[mt][ks] = t;
        }
    __syncthreads();

    for (int hh = 0; hh < HPB; ++hh) {
        const int h = hb * HPB + hh;
        const int colg = h * 64 + wv * 16 + l15;
        const int d    = wv * 16 + l15;

        bf16x8 qbh[4], qbl[4], kbh[4], kbl[4], vbh[4];
#pragma unroll
        for (int ks = 0; ks < 4; ++ks) {
            bf16x8 th, tl, kh_, kl_, vh_;
#pragma unroll
            for (int i = 0; i < 8; ++i) {
                int f = ks * 32 + lg * 8 + i;
                float wq = Wq[f * NHD + colg];
                unsigned short hq = bfc(wq);
                th[i] = (short)hq; tl[i] = (short)bfc(wq - b2f(hq));
                float wk = Wk[f * NHD + colg];
                unsigned short hk = bfc(wk);
                kh_[i] = (short)hk; kl_[i] = (short)bfc(wk - b2f(hk));
                vh_[i] = (short)bfc(Wv[f * NHD + colg]);
            }
            qbh[ks] = th; qbl[ks] = tl; kbh[ks] = kh_; kbl[ks] = kl_; vbh[ks] = vh_;
        }
        const float bqv = bq[colg], bkv = bk[colg], bvv = bv[colg];

        for (int mt = 0; mt < 5; ++mt) {
            f32x4 aq = {0,0,0,0}, ak = {0,0,0,0}, av = {0,0,0,0};
            int rowc = mt * 16 + l15; if (rowc > 65) rowc = 65;
#pragma unroll
            for (int ks = 0; ks < 4; ++ks) {
                int sw = rowc * 128 + (((ks * 4 + lg) ^ (rowc & 15)) << 3);
                bf16x8 ah = *(const bf16x8*)&lds[XWPH + sw];
                bf16x8 al = *(const bf16x8*)&lds[XWPL + sw];
                aq = __builtin_amdgcn_mfma_f32_16x16x32_bf16(ah, qbh[ks], aq, 0, 0, 0);
                aq = __builtin_amdgcn_mfma_f32_16x16x32_bf16(ah, qbl[ks], aq, 0, 0, 0);
                aq = __builtin_amdgcn_mfma_f32_16x16x32_bf16(al, qbh[ks], aq, 0, 0, 0);
                ak = __builtin_amdgcn_mfma_f32_16x16x32_bf16(ah, kbh[ks], ak, 0, 0, 0);
                ak = __builtin_amdgcn_mfma_f32_16x16x32_bf16(ah, kbl[ks], ak, 0, 0, 0);
                ak = __builtin_amdgcn_mfma_f32_16x16x32_bf16(al, kbh[ks], ak, 0, 0, 0);
                av = __builtin_amdgcn_mfma_f32_16x16x32_bf16(ah, vbh[ks], av, 0, 0, 0);
            }
#pragma unroll
            for (int r = 0; r < 4; ++r) {
                int s = mt * 16 + lg * 4 + r;
                if (s < NS) {
                    float qv = (aq[r] + bqv) * 0.125f;
                    unsigned short qh_ = bfc(qv);
                    lds[QH + s * 72 + d] = qh_;
                    lds[QL + s * 72 + d] = bfc(qv - b2f(qh_));
                    float kv = ak[r] + bkv;
                    unsigned short kh2 = bfc(kv);
                    lds[KH + s * 72 + d] = kh2;
                    lds[KL + s * 72 + d] = bfc(kv - b2f(kh2));
                    lds[VT_F + d * 72 + s] = bfc(fmaxf(av[r] + bvv, 0.f));
                }
            }
        }
        __syncthreads();

        float pst[2][5][4];
#pragma unroll
        for (int t = 0; t < 2; ++t) {
            const int mt = (t == 0) ? wv : 4;
            const bool act = (t == 0) || (wv == 0);
            if (act) {
                int rowc = mt * 16 + l15; if (rowc > 65) rowc = 65;
                bf16x8 qh2[2], ql2[2];
#pragma unroll
                for (int ks = 0; ks < 2; ++ks) {
                    qh2[ks] = *(const bf16x8*)&lds[QH + rowc * 72 + ks * 32 + lg * 8];
                    ql2[ks] = *(const bf16x8*)&lds[QL + rowc * 72 + ks * 32 + lg * 8];
                }
                f32x4 c[5];
#pragma unroll
                for (int nt = 0; nt < 5; ++nt) {
                    f32x4 acc = {0,0,0,0};
                    int colr = nt * 16 + l15; if (colr > 65) colr = 65;
#pragma unroll
                    for (int ks = 0; ks < 2; ++ks) {
                        bf16x8 khf = *(const bf16x8*)&lds[KH + colr * 72 + ks * 32 + lg * 8];
                        bf16x8 klf = *(const bf16x8*)&lds[KL + colr * 72 + ks * 32 + lg * 8];
                        acc = __builtin_amdgcn_mfma_f32_16x16x32_bf16(qh2[ks], khf, acc, 0, 0, 0);
                        acc = __builtin_amdgcn_mfma_f32_16x16x32_bf16(qh2[ks], klf, acc, 0, 0, 0);
                        acc = __builtin_amdgcn_mfma_f32_16x16x32_bf16(ql2[ks], khf, acc, 0, 0, 0);
                    }
                    c[nt] = acc;
                }
#pragma unroll
                for (int r = 0; r < 4; ++r) {
                    int srow = mt * 16 + lg * 4 + r;
                    int fi = (srow >= 44) ? 2 : ((srow >= 22) ? 1 : 0);
                    float sv[5];
                    float mv = -INFINITY;
#pragma unroll
                    for (int nt = 0; nt < 5; ++nt) {
                        int j = nt * 16 + l15;
                        int fj = (j >= 44) ? 2 : ((j >= 22) ? 1 : 0);
                        float s = c[nt][r];
                        if ((fi == 0 && fj == 2) || (fi == 2 && fj == 0)) s = 0.f;
                        sv[nt] = s;
                        if (j < NS) mv = fmaxf(mv, s);
                    }
#pragma unroll
                    for (int off = 1; off < 16; off <<= 1) mv = fmaxf(mv, __shfl_xor(mv, off));
                    float thr = mv * (1.f / 9.f);
                    float ev[5];
                    float M2 = -INFINITY;
#pragma unroll
                    for (int nt = 0; nt < 5; ++nt) {
                        int j = nt * 16 + l15;
                        float e = (j < NS && fabsf(sv[nt]) > thr) ? sv[nt] : NEGV;
                        ev[nt] = e;
                        M2 = fmaxf(M2, e);
                    }
#pragma unroll
                    for (int off = 1; off < 16; off <<= 1) M2 = fmaxf(M2, __shfl_xor(M2, off));
                    float sum = 0.f;
#pragma unroll
                    for (int nt = 0; nt < 5; ++nt) {
                        float p = __expf(ev[nt] - M2);
                        pst[t][nt][r] = p;
                        sum += p;
                    }
#pragma unroll
                    for (int off = 1; off < 16; off <<= 1) sum += __shfl_xor(sum, off);
                    float inv = 1.f / sum;
#pragma unroll
                    for (int nt = 0; nt < 5; ++nt) pst[t][nt][r] *= inv;
                }
#pragma unroll
                for (int r = 0; r < 4; ++r) {
                    int srow = mt * 16 + lg * 4 + r;
                    if (srow < NS) {
#pragma unroll
                        for (int nt = 0; nt < 4; ++nt)
                            lds[QH + srow * 72 + nt * 16 + l15] = bfc(pst[t][nt][r]);
                        if (l15 < 2) lds[QH + srow * 72 + 64 + l15] = bfc(pst[t][4][r]);
                    }
                }
            }
        }
        __syncthreads();

#pragma unroll
        for (int t5 = 0; t5 < 5; ++t5) {
            int tile = wv * 5 + t5;
            int mt = tile >> 2, nt = tile & 3;
            int rowc = mt * 16 + l15; if (rowc > 65) rowc = 65;
            int dn = nt * 16 + l15;
            f32x4 acc = {0,0,0,0};
#pragma unroll
            for (int ks = 0; ks < 2; ++ks) {
                bf16x8 pa = *(const bf16x8*)&lds[QH + rowc * 72 + ks * 32 + lg * 8];
                bf16x8 vb = *(const bf16x8*)&lds[VT_F + dn * 72 + ks * 32 + lg * 8];
                acc = __builtin_amdgcn_mfma_f32_16x16x32_bf16(pa, vb, acc, 0, 0, 0);
            }
            float v64 = b2f(lds[VT_F + dn * 72 + 64]);
            float v65 = b2f(lds[VT_F + dn * 72 + 65]);
#pragma unroll
            for (int r = 0; r < 4; ++r) {
                int s2 = mt * 16 + lg * 4 + r;
                if (s2 < NS) {
                    float p64 = b2f(lds[QH + s2 * 72 + 64]);
                    float p65 = b2f(lds[QH + s2 * 72 + 65]);
                    OTf[dn * 76 + s2] = acc[r] + p64 * v64 + p65 * v65;
                }
            }
        }
        __syncthreads();

#pragma unroll
        for (int t = 0; t < 2; ++t) {
            f32x4 acc = {0,0,0,0};
            const int d = wv * 16 + l15;
#pragma unroll
            for (int ks = 0; ks < 2; ++ks) {
                f32x4 f0 = *(const f32x4*)&OTf[d * 76 + ks * 32 + lg * 8];
                f32x4 f1 = *(const f32x4*)&OTf[d * 76 + ks * 32 + lg * 8 + 4];
                bf16x8 bb;
#pragma unroll
                for (int i = 0; i < 4; ++i) {
                    bb[i]     = (short)bfc(f0[i]);
                    bb[i + 4] = (short)bfc(f1[i]);
                }
                acc = __builtin_amdgcn_mfma_f32_16x16x32_bf16(wfrag[t][ks], bb, acc, 0, 0, 0);
            }
            float o64 = OTf[d * 76 + 64];
            float o65 = OTf[d * 76 + 65];
#pragma unroll
            for (int r = 0; r < 4; ++r) {
                int jj = t * 16 + lg * 4 + r;
                if (jj < NJ) {
                    float res = acc[r] + Wcls[64 * NJ + jj] * o64
                                       + Wcls[65 * NJ + jj] * o65 + bcls[jj];
                    out[((b * (NW * NJ) + w * NJ + jj) * NHD) + h * 64 + wv * 16 + l15] = res;
                }
            }
        }
        __syncthreads();
    }
}

__global__ __launch_bounds__(256) void ft_ln_kernel(
    const float* __restrict__ Wft, const float* __restrict__ bft,
    const float* __restrict__ a2, const float* __restrict__ b2,
    float* __restrict__ out)
{
    __shared__ float sA[16 * NOUT];
    const int tid = threadIdx.x;
    const int base = blockIdx.x * (16 * NOUT);

    for (int idx = tid; idx < 16 * NOUT; idx += 256) sA[idx] = out[base + idx];
    __syncthreads();

    float a0[16], a1[16];
    const float bf0 = bft[tid], bf1 = bft[tid + 256];
#pragma unroll
    for (int r = 0; r < 16; ++r) { a0[r] = bf0; a1[r] = bf1; }

    for (int f = 0; f < NOUT; ++f) {
        float w0 = Wft[f * NOUT + tid];
        float w1 = Wft[f * NOUT + tid + 256];
#pragma unroll
        for (int r = 0; r < 16; ++r) {
            float a = sA[r * NOUT + f];
            a0[r] = fmaf(a, w0, a0[r]);
            a1[r] = fmaf(a, w1, a1[r]);
        }
    }
    __syncthreads();
#pragma unroll
    for (int r = 0; r < 16; ++r) {
        sA[r * NOUT + tid]       = fmaxf(a0[r], 0.f);
        sA[r * NOUT + tid + 256] = fmaxf(a1[r], 0.f);
    }
    __syncthreads();

    const int lane = tid & 63, wvv = tid >> 6;
    for (int r = wvv * 4; r < wvv * 4 + 4; ++r) {
        float s = 0.f, sq = 0.f;
        float vals[8];
#pragma unroll
        for (int u = 0; u < 8; ++u) {
            float y = sA[r * NOUT + u * 64 + lane];
            vals[u] = y;
            s += y;
            sq = fmaf(y, y, sq);
        }
#pragma unroll
        for (int off = 32; off; off >>= 1) {
            s  += __shfl_xor(s,  off);
            sq += __shfl_xor(sq, off);
        }
        float mean = s * (1.0f / 512.0f);
        float var  = fmaxf((sq - 512.0f * mean * mean) * (1.0f / 511.0f), 0.0f);
        float inv  = 1.0f / (sqrtf(var) + 1e-6f);
#pragma unroll
        for (int u = 0; u < 8; ++u) {
            int c = u * 64 + lane;
            out[base + r * NOUT + c] = a2[c] * (vals[u] - mean) * inv + b2[c];
        }
    }
}

extern "C" void kernel_launch(void* const* d_in, const int* in_sizes, int n_in,
                              void* d_out, int out_size, void* d_ws, size_t ws_size,
                              hipStream_t stream) {
    (void)in_sizes; (void)n_in; (void)out_size;
    const float* x    = (const float*)d_in[0];
    const float* Wq   = (const float*)d_in[1];
    const float* bq   = (const float*)d_in[2];
    const float* Wk   = (const float*)d_in[3];
    const float* bk   = (const float*)d_in[4];
    const float* Wv   = (const float*)d_in[5];
    const float* bv   = (const float*)d_in[6];
    const float* Wcls = (const float*)d_in[7];
    const float* bcls = (const float*)d_in[8];
    const float* Wft  = (const float*)d_in[9];
    const float* bft  = (const float*)d_in[10];
    const float* a2   = (const float*)d_in[11];
    const float* b2   = (const float*)d_in[12];
    float* out = (float*)d_out;

    if (ws_size >= WS_FULL_BYTES) {
        unsigned short* ws = (unsigned short*)d_ws;
        prep_kernel<<<1880, 256, 0, stream>>>(Wq, Wk, Wv, Wft, ws);
        qkv_kernel<<<1056, 256, 0, stream>>>(x, bq, bk, bv, ws, ws);
        attn_kernel12<<<(NB * NW * NH) / 4, 256, 0, stream>>>(ws, Wcls, bcls, out);
        ft_ln4<<<528, 256, 0, stream>>>(ws, bft, a2, b2, out);
    } else {
        attn_kernel<<<NB * NW * 2, 256, 0, stream>>>(x, Wq, bq, Wk, bk, Wv, bv,
                                                     Wcls, bcls, out);
        ft_ln_kernel<<<(NB * NW * NJ) / 16, 256, 0, stream>>>(Wft, bft, a2, b2, out);
    }
}

// Round 20
// 249.738 us; speedup vs baseline: 1.2572x; 1.2572x over previous
//
#include <hip/hip_runtime.h>
#include <math.h>

#define NB 128
#define NT 8
#define NJ 22
#define NF 128
#define NH 8
#define NDH 64
#define NS 66     // 3*NJ
#define NW 6      // NT-2
#define NOUT 512
#define NHD 512   // NH*NDH
#define NEGV -9e15f
#define RTOT 22528   // B*T*J

typedef short bf16x8 __attribute__((ext_vector_type(8)));
typedef float f32x4  __attribute__((ext_vector_type(4)));
typedef unsigned int uint4v __attribute__((ext_vector_type(4)));

// ---- workspace layout (ushort offsets) ----
#define WQH 0          // prepped W^T hi/lo: [512][128]
#define WQL 65536
#define WKH 131072
#define WKL 196608
#define WVT 262144
#define WFH 327680     // WftT hi [512][512]
#define WFL 589824
#define PEU 851968     // PE fp32 table [176][128]
#define GQP 897024     // q packed hi|lo<<16: uint32 [8][22528][64]
#define GKP 23965696   // k packed
#define GVR 47034368   // v row-major ushort [8][128][176][64]
#define HS  1441792    // per-head plane stride in ELEMENTS ([22528][64])
#define VBS 11264      // 176*64
#define WS_FULL_BYTES 117137408ULL

// ---- LDS regions for ultra-fallback attn kernel (ushort offsets) ----
#define XWPH 0
#define XWPL 8448
#define QH   16896
#define QL   21648
#define KH   26400
#define KL   31152
#define OTF_U 26400
#define VT_F 36128
#define LDS_USHORT 40736

__device__ __forceinline__ unsigned short bfc(float f) {
    union { float f; unsigned u; } v; v.f = f;
    unsigned r = v.u + 0x7FFFu + ((v.u >> 16) & 1u);
    return (unsigned short)(r >> 16);
}
__device__ __forceinline__ float b2f(unsigned short h) {
    union { unsigned u; float f; } v; v.u = ((unsigned)h) << 16;
    return v.f;
}
// unpack 8 dwords (hi|lo<<16) -> hi-bf16x8, lo-bf16x8
__device__ __forceinline__ void unpack_hl(const unsigned int* p, bf16x8* hi, bf16x8* lo) {
    uint4v a = *(const uint4v*)p;
    uint4v b = *(const uint4v*)(p + 4);
    union { unsigned int u[4]; bf16x8 v; } H, L;
    H.u[0] = __builtin_amdgcn_perm(a[1], a[0], 0x05040100u);
    H.u[1] = __builtin_amdgcn_perm(a[3], a[2], 0x05040100u);
    H.u[2] = __builtin_amdgcn_perm(b[1], b[0], 0x05040100u);
    H.u[3] = __builtin_amdgcn_perm(b[3], b[2], 0x05040100u);
    L.u[0] = __builtin_amdgcn_perm(a[1], a[0], 0x07060302u);
    L.u[1] = __builtin_amdgcn_perm(a[3], a[2], 0x07060302u);
    L.u[2] = __builtin_amdgcn_perm(b[1], b[0], 0x07060302u);
    L.u[3] = __builtin_amdgcn_perm(b[3], b[2], 0x07060302u);
    *hi = H.v; *lo = L.v;
}

// ---------------------------------------------------------------------------
// prep: W panels (transpose + hi/lo split) + PE fp32 table
// ---------------------------------------------------------------------------
__global__ __launch_bounds__(256) void prep_kernel(
    const float* __restrict__ Wq, const float* __restrict__ Wk,
    const float* __restrict__ Wv, const float* __restrict__ Wft,
    unsigned short* __restrict__ ws)
{
    int idx = blockIdx.x * 256 + threadIdx.x;
    if (idx < 196608) {
        int m = idx >> 16;
        int r = idx & 65535;
        int col = r >> 7, f = r & 127;
        const float* W = (m == 0) ? Wq : ((m == 1) ? Wk : Wv);
        float v = W[f * NHD + col];
        unsigned short h = bfc(v);
        if (m == 0)      { ws[WQH + r] = h; ws[WQL + r] = bfc(v - b2f(h)); }
        else if (m == 1) { ws[WKH + r] = h; ws[WKL + r] = bfc(v - b2f(h)); }
        else             { ws[WVT + r] = h; }
    } else if (idx < 458752) {
        int r = idx - 196608;
        int col = r >> 9, f = r & 511;
        float v = Wft[f * NOUT + col];
        unsigned short h = bfc(v);
        ws[WFH + r] = h;
        ws[WFL + r] = bfc(v - b2f(h));
    } else {
        int r = idx - 458752;          // [tj][f]
        int tj = r >> 7, f = r & 127;
        int t = tj / 22, j = tj - t * 22;
        const float cdiv = -0.0719557841560639f;
        float dv = __expf(cdiv * (float)(f & ~1));
        float pe = ((f & 1) == 0) ? (__sinf((float)j * dv) + __sinf((float)t * dv))
                                  : (__cosf((float)j * dv) + __cosf((float)t * dv));
        ((float*)(ws + PEU))[r] = pe;
    }
}

// ---------------------------------------------------------------------------
// Phase 1: QKV projection GEMM. M=64/block, XCD-aligned: XCD x produces
// batches [16x,16x+16). Full 16-fragment B burst per ka. grid 1056. (256,2).
// ---------------------------------------------------------------------------
__global__ __launch_bounds__(256, 2) void qkv_kernel(
    const float* __restrict__ x,
    const float* __restrict__ bq, const float* __restrict__ bk,
    const float* __restrict__ bv,
    const unsigned short* __restrict__ ws,
    unsigned short* __restrict__ wso)
{
    __shared__ __align__(16) unsigned short ah[64 * 136];
    __shared__ __align__(16) unsigned short al[64 * 136];
    const int tid = threadIdx.x, lane = tid & 63, wv = tid >> 6;
    const int l15 = lane & 15, lg = lane >> 4;
    // XCD-aligned work mapping: t8 = XCD, 132 blocks each (44 row-blocks x 3 mats)
    const int t8 = blockIdx.x & 7;
    const int s8 = blockIdx.x >> 3;
    const int mat  = s8 % 3;
    const int row0 = (44 * t8 + s8 / 3) * 64;
    const float* PEf = (const float*)(ws + PEU);

    const int tjbase = row0 % 176;
    for (int idx = tid; idx < 64 * 32; idx += 256) {
        int rr = idx >> 5, f4 = (idx & 31) * 4;
        int tj = tjbase + rr; if (tj >= 176) tj -= 176;
        f32x4 xv = *(const f32x4*)&x[(row0 + rr) * NF + f4];
        f32x4 pe = *(const f32x4*)&PEf[tj * 128 + f4];
#pragma unroll
        for (int i = 0; i < 4; ++i) {
            float val = xv[i] + pe[i];
            unsigned short hs = bfc(val);
            ah[rr * 136 + f4 + i] = hs;
            al[rr * 136 + f4 + i] = bfc(val - b2f(hs));
        }
    }
    __syncthreads();

    const unsigned short* WH = (mat == 0) ? (ws + WQH) : ((mat == 1) ? (ws + WKH) : (ws + WVT));
    const unsigned short* WL = (mat == 0) ? (ws + WQL) : (ws + WKL);
    const float* bias = (mat == 0) ? bq : ((mat == 1) ? bk : bv);

    f32x4 acc[4][8];
#pragma unroll
    for (int m = 0; m < 4; ++m)
#pragma unroll
        for (int g = 0; g < 8; ++g) acc[m][g] = (f32x4){0, 0, 0, 0};

#pragma unroll
    for (int ka = 0; ka < 4; ++ka) {
        bf16x8 bhA[8], blA[8];
#pragma unroll
        for (int g = 0; g < 8; ++g) {
            int col = (wv * 8 + g) * 16 + l15;
            bhA[g] = *(const bf16x8*)&WH[col * 128 + ka * 32 + lg * 8];
        }
        if (mat < 2) {
#pragma unroll
            for (int g = 0; g < 8; ++g) {
                int col = (wv * 8 + g) * 16 + l15;
                blA[g] = *(const bf16x8*)&WL[col * 128 + ka * 32 + lg * 8];
            }
        }
        bf16x8 afh[4], afl[4];
#pragma unroll
        for (int m = 0; m < 4; ++m) {
            afh[m] = *(const bf16x8*)&ah[(m * 16 + l15) * 136 + ka * 32 + lg * 8];
            afl[m] = *(const bf16x8*)&al[(m * 16 + l15) * 136 + ka * 32 + lg * 8];
        }
#pragma unroll
        for (int g = 0; g < 8; ++g) {
#pragma unroll
            for (int m = 0; m < 4; ++m)
                acc[m][g] = __builtin_amdgcn_mfma_f32_16x16x32_bf16(afh[m], bhA[g], acc[m][g], 0, 0, 0);
            if (mat < 2) {
#pragma unroll
                for (int m = 0; m < 4; ++m) {
                    acc[m][g] = __builtin_amdgcn_mfma_f32_16x16x32_bf16(afh[m], blA[g], acc[m][g], 0, 0, 0);
                    acc[m][g] = __builtin_amdgcn_mfma_f32_16x16x32_bf16(afl[m], bhA[g], acc[m][g], 0, 0, 0);
                }
            }
        }
    }

#pragma unroll
    for (int g = 0; g < 8; ++g) {
        int cg = wv * 8 + g;
        int colg = cg * 16 + l15;
        int h2 = cg >> 2;
        int c = (cg & 3) * 16 + l15;
        float bv_ = bias[colg];
        if (mat == 2) {
#pragma unroll
            for (int m = 0; m < 4; ++m)
#pragma unroll
                for (int r = 0; r < 4; ++r) {
                    int row = row0 + m * 16 + lg * 4 + r;
                    int bb = row / 176;
                    int tj = row - bb * 176;
                    wso[GVR + (size_t)(h2 * NB + bb) * VBS + tj * 64 + c] =
                        bfc(fmaxf(acc[m][g][r] + bv_, 0.f));
                }
        } else {
            unsigned int* OP = (unsigned int*)(wso + ((mat == 0) ? GQP : GKP)) + (size_t)h2 * HS;
            const float scale = (mat == 0) ? 0.125f : 1.0f;
#pragma unroll
            for (int m = 0; m < 4; ++m)
#pragma unroll
                for (int r = 0; r < 4; ++r) {
                    int row = row0 + m * 16 + lg * 4 + r;
                    float v = (acc[m][g][r] + bv_) * scale;
                    unsigned short h = bfc(v);
                    unsigned short l = bfc(v - b2f(h));
                    OP[row * 64 + c] = (unsigned int)h | ((unsigned int)l << 16);
                }
        }
    }
}

// ---------------------------------------------------------------------------
// Phase 2 (attn12): ONE WAVE per (b,w,h), window-fastest gid, XCD-aligned.
// K register-resident; V transposed through P scratch; softmax shift = mv.
// ---------------------------------------------------------------------------
#define PWS7 4752

__global__ __launch_bounds__(256, 2) void attn_kernel12(
    const unsigned short* __restrict__ ws,
    const float* __restrict__ Wcls, const float* __restrict__ bcls,
    float* __restrict__ out)
{
    __shared__ __align__(16) unsigned short lds[4 * PWS7];   // 38016 B
    const int tid  = threadIdx.x;
    const int lane = tid & 63;
    const int wv   = tid >> 6;
    const int l15  = lane & 15;
    const int lg   = lane >> 4;
    const int nbid = ((blockIdx.x & 7) * 192) + (blockIdx.x >> 3);  // XCD swizzle
    const int gid  = nbid * 4 + wv;
    const int w = gid % 6;
    const int h = (gid / 6) & 7;
    const int b = gid / 48;
    const int rowbase = b * 176 + w * 22;
    unsigned short* P = lds + wv * PWS7;

    const unsigned int* qpb = (const unsigned int*)(ws + GQP) + (size_t)h * HS + rowbase * 64;
    const unsigned int* kpb = (const unsigned int*)(ws + GKP) + (size_t)h * HS + rowbase * 64;
    const unsigned short* vrb = ws + GVR + (size_t)(h * NB + b) * VBS + (w * 22) * 64;

    // ---- prefetch ALL of K (packed) -> registers, unpack to hi/lo ----
    bf16x8 kh_r[5][2], kl_r[5][2];
#pragma unroll
    for (int nt = 0; nt < 5; ++nt) {
        int colr = nt * 16 + l15; if (colr > 65) colr = 65;
#pragma unroll
        for (int ks = 0; ks < 2; ++ks)
            unpack_hl(&kpb[colr * 64 + ks * 32 + lg * 8], &kh_r[nt][ks], &kl_r[nt][ks]);
    }

    // ---- stage V (row-major) -> P region transposed [d][s] ----
#pragma unroll
    for (int it = 0; it < 8; ++it) {
        bf16x8 vvv = *(const bf16x8*)&vrb[lane * 64 + it * 8];   // s=lane
#pragma unroll
        for (int i = 0; i < 8; ++i) P[(it * 8 + i) * 72 + lane] = (unsigned short)vvv[i];
    }
    if (lane < 16) {
        int s2 = 64 + (lane & 1);
        int o2 = lane >> 1;
        bf16x8 vvv = *(const bf16x8*)&vrb[s2 * 64 + o2 * 8];
#pragma unroll
        for (int i = 0; i < 8; ++i) P[(o2 * 8 + i) * 72 + s2] = (unsigned short)vvv[i];
    }

    // ---- Wcls A-fragments (independent; executes in the V/K miss shadow) ----
    bf16x8 wfrag[2][2];
#pragma unroll
    for (int mt = 0; mt < 2; ++mt)
#pragma unroll
        for (int ks = 0; ks < 2; ++ks) {
            int j = mt * 16 + l15;
            bf16x8 t;
#pragma unroll
            for (int i = 0; i < 8; ++i) {
                int s = ks * 32 + lg * 8 + i;
                float v = (j < NJ) ? Wcls[s * NJ + j] : 0.f;
                t[i] = (short)bfc(v);
            }
            wfrag[mt][ks] = t;
        }

    asm volatile("s_waitcnt lgkmcnt(0)" ::: "memory");
    __builtin_amdgcn_sched_barrier(0);

    bf16x8 vreg[4][2];
    float v64r[4], v65r[4];
#pragma unroll
    for (int nt = 0; nt < 4; ++nt) {
        const int dn = nt * 16 + l15;
        vreg[nt][0] = *(const bf16x8*)&P[dn * 72 + lg * 8];
        vreg[nt][1] = *(const bf16x8*)&P[dn * 72 + 32 + lg * 8];
        unsigned int vv = *(const unsigned int*)&P[dn * 72 + 64];
        v64r[nt] = b2f((unsigned short)(vv & 0xffffu));
        v65r[nt] = b2f((unsigned short)(vv >> 16));
    }
    asm volatile("s_waitcnt lgkmcnt(0)" ::: "memory");
    __builtin_amdgcn_sched_barrier(0);

    // ---- scores + mask + threshold + softmax (shift = mv) -> P ----
#pragma unroll
    for (int mt = 0; mt < 5; ++mt) {
        int rowc = mt * 16 + l15; if (rowc > 65) rowc = 65;
        bf16x8 qh2[2], ql2[2];
#pragma unroll
        for (int ks = 0; ks < 2; ++ks)
            unpack_hl(&qpb[rowc * 64 + ks * 32 + lg * 8], &qh2[ks], &ql2[ks]);
        f32x4 c[5];
#pragma unroll
        for (int nt = 0; nt < 5; ++nt) {
            f32x4 acc = {0, 0, 0, 0};
#pragma unroll
            for (int ks = 0; ks < 2; ++ks) {
                acc = __builtin_amdgcn_mfma_f32_16x16x32_bf16(qh2[ks], kh_r[nt][ks], acc, 0, 0, 0);
                acc = __builtin_amdgcn_mfma_f32_16x16x32_bf16(qh2[ks], kl_r[nt][ks], acc, 0, 0, 0);
                acc = __builtin_amdgcn_mfma_f32_16x16x32_bf16(ql2[ks], kh_r[nt][ks], acc, 0, 0, 0);
            }
            c[nt] = acc;
        }
#pragma unroll
        for (int r = 0; r < 4; ++r) {
            int srow = mt * 16 + lg * 4 + r;
            int fi = (srow >= 44) ? 2 : ((srow >= 22) ? 1 : 0);
            float sv[5];
            float mv = -INFINITY;
#pragma unroll
            for (int nt = 0; nt < 5; ++nt) {
                int j = nt * 16 + l15;
                int fj = (j >= 44) ? 2 : ((j >= 22) ? 1 : 0);
                float s = c[nt][r];
                if ((fi == 0 && fj == 2) || (fi == 2 && fj == 0)) s = 0.f;
                sv[nt] = s;
                if (j < NS) mv = fmaxf(mv, s);
            }
#pragma unroll
            for (int off = 1; off < 16; off <<= 1) mv = fmaxf(mv, __shfl_xor(mv, off));
            float thr = mv * (1.f / 9.f);
            float pv5[5];
            float sum = 0.f;
#pragma unroll
            for (int nt = 0; nt < 5; ++nt) {
                int j = nt * 16 + l15;
                float e = (j < NS && fabsf(sv[nt]) > thr) ? sv[nt] : NEGV;
                float p = __expf(e - mv);
                pv5[nt] = p;
                sum += p;
            }
#pragma unroll
            for (int off = 1; off < 16; off <<= 1) sum += __shfl_xor(sum, off);
            float inv = 1.f / sum;
            if (srow < NS) {
#pragma unroll
                for (int nt = 0; nt < 5; ++nt) {
                    unsigned short ph = bfc(pv5[nt] * inv);
                    if (nt < 4)           P[srow * 72 + nt * 16 + l15] = ph;
                    else if (l15 < 2)     P[srow * 72 + 64 + l15]      = ph;
                }
            }
        }
    }
    asm volatile("s_waitcnt lgkmcnt(0)" ::: "memory");
    __builtin_amdgcn_sched_barrier(0);

    // ---- PV + in-register Wcls, per d-tile nt ----
#pragma unroll
    for (int nt = 0; nt < 4; ++nt) {
        const int dn = nt * 16 + l15;
        const float v64 = v64r[nt];
        const float v65 = v65r[nt];

        f32x4 o[5];
#pragma unroll
        for (int mt = 0; mt < 5; ++mt) {
            int rowc = mt * 16 + l15; if (rowc > 65) rowc = 65;
            f32x4 a = {0, 0, 0, 0};
#pragma unroll
            for (int ks = 0; ks < 2; ++ks) {
                bf16x8 pa = *(const bf16x8*)&P[rowc * 72 + ks * 32 + lg * 8];
                a = __builtin_amdgcn_mfma_f32_16x16x32_bf16(pa, vreg[nt][ks], a, 0, 0, 0);
            }
#pragma unroll
            for (int r = 0; r < 4; ++r) {
                int s2 = mt * 16 + lg * 4 + r;
                if (s2 < NS) {
                    float p64 = b2f(P[s2 * 72 + 64]);
                    float p65 = b2f(P[s2 * 72 + 65]);
                    a[r] += p64 * v64 + p65 * v65;
                }
            }
            o[mt] = a;
        }

        unsigned int pk0[4], pk1[4];
#pragma unroll
        for (int mt = 0; mt < 4; ++mt) {
            pk0[mt] = (unsigned int)bfc(o[mt][0]) | ((unsigned int)bfc(o[mt][1]) << 16);
            pk1[mt] = (unsigned int)bfc(o[mt][2]) | ((unsigned int)bfc(o[mt][3]) << 16);
        }
        const int L0 = l15 + 16 * ((lg & 1) * 2);
        const int L1 = L0 + 16;
        const bool hiSel = (lg >> 1) & 1;

        bf16x8 bfr[2];
#pragma unroll
        for (int ks2 = 0; ks2 < 2; ++ks2) {
            unsigned int s00 = __shfl((int)pk0[2 * ks2],     L0);
            unsigned int s01 = __shfl((int)pk1[2 * ks2],     L0);
            unsigned int s10 = __shfl((int)pk0[2 * ks2 + 1], L0);
            unsigned int s11 = __shfl((int)pk1[2 * ks2 + 1], L0);
            unsigned int t00 = __shfl((int)pk0[2 * ks2],     L1);
            unsigned int t01 = __shfl((int)pk1[2 * ks2],     L1);
            unsigned int t10 = __shfl((int)pk0[2 * ks2 + 1], L1);
            unsigned int t11 = __shfl((int)pk1[2 * ks2 + 1], L1);
            uint4v dw;
            dw[0] = hiSel ? s10 : s00;
            dw[1] = hiSel ? s11 : s01;
            dw[2] = hiSel ? t10 : t00;
            dw[3] = hiSel ? t11 : t01;
            union { uint4v u; bf16x8 b; } cv; cv.u = dw;
            bfr[ks2] = cv.b;
        }
        const float o64 = __shfl(o[4][0], l15);
        const float o65 = __shfl(o[4][1], l15);

        f32x4 C2[2];
#pragma unroll
        for (int jt = 0; jt < 2; ++jt) {
            f32x4 a = {0, 0, 0, 0};
#pragma unroll
            for (int ks2 = 0; ks2 < 2; ++ks2)
                a = __builtin_amdgcn_mfma_f32_16x16x32_bf16(wfrag[jt][ks2], bfr[ks2], a, 0, 0, 0);
            C2[jt] = a;
        }
#pragma unroll
        for (int jt = 0; jt < 2; ++jt) {
#pragma unroll
            for (int r = 0; r < 4; ++r) {
                int jj = jt * 16 + lg * 4 + r;
                if (jj < NJ) {
                    float res = C2[jt][r] + Wcls[64 * NJ + jj] * o64
                                          + Wcls[65 * NJ + jj] * o65 + bcls[jj];
                    out[((b * (NW * NJ) + w * NJ + jj) * NHD) + h * 64 + dn] = res;
                }
            }
        }
    }
}

// ---------------------------------------------------------------------------
// ft v4: M=32/block; 16-load B burst; XCD-aligned with attn's out writes.
// ---------------------------------------------------------------------------
__global__ __launch_bounds__(256, 2) void ft_ln4(
    const unsigned short* __restrict__ ws,
    const float* __restrict__ bft,
    const float* __restrict__ a2, const float* __restrict__ b2,
    float* __restrict__ out)
{
    __shared__ __align__(16) unsigned short sAH[32 * 536];
    __shared__ __align__(16) unsigned short sAL[32 * 536];
    __shared__ float red[2][4][32];
    const int tid = threadIdx.x, lane = tid & 63, wv = tid >> 6;
    const int l15 = lane & 15, lg = lane >> 4;
    const int nb = (blockIdx.x & 7) * 66 + (blockIdx.x >> 3);
    const int base = nb * (32 * NOUT);

    for (int idx = tid; idx < 32 * NOUT; idx += 256) {
        int r = idx >> 9, c = idx & 511;
        float v = out[base + idx];
        unsigned short h = bfc(v);
        sAH[r * 536 + c] = h;
        sAL[r * 536 + c] = bfc(v - b2f(h));
    }
    __syncthreads();

    f32x4 acc[2][8];
#pragma unroll
    for (int m = 0; m < 2; ++m)
#pragma unroll
        for (int g = 0; g < 8; ++g) acc[m][g] = (f32x4){0, 0, 0, 0};

    for (int ka = 0; ka < 16; ++ka) {
        bf16x8 bh[8], bl[8];
#pragma unroll
        for (int g = 0; g < 8; ++g) {
            int col = (wv * 8 + g) * 16 + l15;
            bh[g] = *(const bf16x8*)&ws[WFH + col * 512 + ka * 32 + lg * 8];
            bl[g] = *(const bf16x8*)&ws[WFL + col * 512 + ka * 32 + lg * 8];
        }
        bf16x8 afh[2], afl[2];
#pragma unroll
        for (int m = 0; m < 2; ++m) {
            afh[m] = *(const bf16x8*)&sAH[(m * 16 + l15) * 536 + ka * 32 + lg * 8];
            afl[m] = *(const bf16x8*)&sAL[(m * 16 + l15) * 536 + ka * 32 + lg * 8];
        }
#pragma unroll
        for (int g = 0; g < 8; ++g) {
#pragma unroll
            for (int m = 0; m < 2; ++m) {
                acc[m][g] = __builtin_amdgcn_mfma_f32_16x16x32_bf16(afh[m], bh[g], acc[m][g], 0, 0, 0);
                acc[m][g] = __builtin_amdgcn_mfma_f32_16x16x32_bf16(afh[m], bl[g], acc[m][g], 0, 0, 0);
                acc[m][g] = __builtin_amdgcn_mfma_f32_16x16x32_bf16(afl[m], bh[g], acc[m][g], 0, 0, 0);
            }
        }
    }

#pragma unroll
    for (int g = 0; g < 8; ++g) {
        int col = (wv * 8 + g) * 16 + l15;
        float bfv = bft[col];
#pragma unroll
        for (int m = 0; m < 2; ++m)
#pragma unroll
            for (int r = 0; r < 4; ++r)
                acc[m][g][r] = fmaxf(acc[m][g][r] + bfv, 0.f);
    }

    float ps[2][4], pq[2][4];
#pragma unroll
    for (int m = 0; m < 2; ++m)
#pragma unroll
        for (int r = 0; r < 4; ++r) {
            float s = 0.f, q = 0.f;
#pragma unroll
            for (int g = 0; g < 8; ++g) {
                s += acc[m][g][r];
                q = fmaf(acc[m][g][r], acc[m][g][r], q);
            }
            ps[m][r] = s; pq[m][r] = q;
        }
#pragma unroll
    for (int off = 1; off < 16; off <<= 1) {
#pragma unroll
        for (int m = 0; m < 2; ++m)
#pragma unroll
            for (int r = 0; r < 4; ++r) {
                ps[m][r] += __shfl_xor(ps[m][r], off);
                pq[m][r] += __shfl_xor(pq[m][r], off);
            }
    }
    if (l15 == 0) {
#pragma unroll
        for (int m = 0; m < 2; ++m)
#pragma unroll
            for (int r = 0; r < 4; ++r) {
                int row = m * 16 + lg * 4 + r;
                red[0][wv][row] = ps[m][r];
                red[1][wv][row] = pq[m][r];
            }
    }
    __syncthreads();

    float mean[2][4], inv[2][4];
#pragma unroll
    for (int m = 0; m < 2; ++m)
#pragma unroll
        for (int r = 0; r < 4; ++r) {
            int row = m * 16 + lg * 4 + r;
            float s = red[0][0][row] + red[0][1][row] + red[0][2][row] + red[0][3][row];
            float q = red[1][0][row] + red[1][1][row] + red[1][2][row] + red[1][3][row];
            float mn = s * (1.0f / 512.0f);
            float var = fmaxf((q - 512.0f * mn * mn) * (1.0f / 511.0f), 0.0f);
            mean[m][r] = mn;
            inv[m][r] = 1.0f / (sqrtf(var) + 1e-6f);
        }
#pragma unroll
    for (int g = 0; g < 8; ++g) {
        int col = (wv * 8 + g) * 16 + l15;
        float av2 = a2[col], bv2 = b2[col];
#pragma unroll
        for (int m = 0; m < 2; ++m)
#pragma unroll
            for (int r = 0; r < 4; ++r) {
                int row = m * 16 + lg * 4 + r;
                out[base + row * NOUT + col] = av2 * (acc[m][g][r] - mean[m][r]) * inv[m][r] + bv2;
            }
    }
}

// ===========================================================================
// Ultra fallback (no ws): self-contained attn + fp32 ft/LN (proven R3 path)
// ===========================================================================
__global__ __launch_bounds__(256) void attn_kernel(
    const float* __restrict__ x,
    const float* __restrict__ Wq, const float* __restrict__ bq,
    const float* __restrict__ Wk, const float* __restrict__ bk,
    const float* __restrict__ Wv, const float* __restrict__ bv,
    const float* __restrict__ Wcls, const float* __restrict__ bcls,
    float* __restrict__ out)
{
    __shared__ __align__(16) unsigned short lds[LDS_USHORT];
    float* OTf = (float*)&lds[OTF_U];

    const int tid  = threadIdx.x;
    const int lane = tid & 63;
    const int wv   = tid >> 6;
    const int l15  = lane & 15;
    const int lg   = lane >> 4;
    const int bid  = blockIdx.x;
    const int hb   = bid & 1;
    const int w    = (bid >> 1) % NW;
    const int b    = bid / (2 * NW);

    const float cdiv = -0.0719557841560639f;
    for (int idx = tid; idx < NS * NF; idx += 256) {
        int s = idx >> 7, f = idx & 127;
        int i = (s >= 44) ? 2 : ((s >= 22) ? 1 : 0);
        int j = s - i * NJ;
        int fr = w + i;
        float xv = x[((b * NT + fr) * NJ + j) * NF + f];
        float dv = __expf(cdiv * (float)(f & ~1));
        float pe = ((f & 1) == 0) ? (__sinf((float)j * dv) + __sinf((float)fr * dv))
                                  : (__cosf((float)j * dv) + __cosf((float)fr * dv));
        float val = xv + pe;
        unsigned short hs = bfc(val);
        int addr = s * 128 + ((((f >> 3) ^ (s & 15))) << 3) + (f & 7);
        lds[XWPH + addr] = hs;
        lds[XWPL + addr] = bfc(val - b2f(hs));
    }

    bf16x8 wfrag[2][2];
#pragma unroll
    for (int mt = 0; mt < 2; ++mt)
#pragma unroll
        for (int ks = 0; ks < 2; ++ks) {
            int j = mt * 16 + l15;
            bf16x8 t;
#pragma unroll
            for (int i = 0; i < 8; ++i) {
                int s = ks * 32 + lg * 8 + i;
                float v = (j < NJ) ? Wcls[s * NJ + j] : 0.f;
                t[i] = (short)bfc(v);
            }
            wfrag[mt][ks] = t;
        }
    __syncthreads();

    for (int hh = 0; hh < 4; ++hh) {
        const int h = hb * 4 + hh;
        const int colg = h * 64 + wv * 16 + l15;
        const int d    = wv * 16 + l15;

        bf16x8 qbh[4], qbl[4], kbh[4], kbl[4], vbh[4];
#pragma unroll
        for (int ks = 0; ks < 4; ++ks) {
            bf16x8 th, tl, kh_, kl_, vh_;
#pragma unroll
            for (int i = 0; i < 8; ++i) {
                int f = ks * 32 + lg * 8 + i;
                float wq = Wq[f * NHD + colg];
                unsigned short hq = bfc(wq);
                th[i] = (short)hq; tl[i] = (short)bfc(wq - b2f(hq));
                float wk = Wk[f * NHD + colg];
                unsigned short hk = bfc(wk);
                kh_[i] = (short)hk; kl_[i] = (short)bfc(wk - b2f(hk));
                vh_[i] = (short)bfc(Wv[f * NHD + colg]);
            }
            qbh[ks] = th; qbl[ks] = tl; kbh[ks] = kh_; kbl[ks] = kl_; vbh[ks] = vh_;
        }
        const float bqv = bq[colg], bkv = bk[colg], bvv = bv[colg];

        for (int mt = 0; mt < 5; ++mt) {
            f32x4 aq = {0,0,0,0}, ak = {0,0,0,0}, av = {0,0,0,0};
            int rowc = mt * 16 + l15; if (rowc > 65) rowc = 65;
#pragma unroll
            for (int ks = 0; ks < 4; ++ks) {
                int sw = rowc * 128 + (((ks * 4 + lg) ^ (rowc & 15)) << 3);
                bf16x8 ah = *(const bf16x8*)&lds[XWPH + sw];
                bf16x8 al = *(const bf16x8*)&lds[XWPL + sw];
                aq = __builtin_amdgcn_mfma_f32_16x16x32_bf16(ah, qbh[ks], aq, 0, 0, 0);
                aq = __builtin_amdgcn_mfma_f32_16x16x32_bf16(ah, qbl[ks], aq, 0, 0, 0);
                aq = __builtin_amdgcn_mfma_f32_16x16x32_bf16(al, qbh[ks], aq, 0, 0, 0);
                ak = __builtin_amdgcn_mfma_f32_16x16x32_bf16(ah, kbh[ks], ak, 0, 0, 0);
                ak = __builtin_amdgcn_mfma_f32_16x16x32_bf16(ah, kbl[ks], ak, 0, 0, 0);
                ak = __builtin_amdgcn_mfma_f32_16x16x32_bf16(al, kbh[ks], ak, 0, 0, 0);
                av = __builtin_amdgcn_mfma_f32_16x16x32_bf16(ah, vbh[ks], av, 0, 0, 0);
            }
#pragma unroll
            for (int r = 0; r < 4; ++r) {
                int s = mt * 16 + lg * 4 + r;
                if (s < NS) {
                    float qv = (aq[r] + bqv) * 0.125f;
                    unsigned short qh_ = bfc(qv);
                    lds[QH + s * 72 + d] = qh_;
                    lds[QL + s * 72 + d] = bfc(qv - b2f(qh_));
                    float kv = ak[r] + bkv;
                    unsigned short kh2 = bfc(kv);
                    lds[KH + s * 72 + d] = kh2;
                    lds[KL + s * 72 + d] = bfc(kv - b2f(kh2));
                    lds[VT_F + d * 72 + s] = bfc(fmaxf(av[r] + bvv, 0.f));
                }
            }
        }
        __syncthreads();

        float pst[2][5][4];
#pragma unroll
        for (int t = 0; t < 2; ++t) {
            const int mt = (t == 0) ? wv : 4;
            const bool act = (t == 0) || (wv == 0);
            if (act) {
                int rowc = mt * 16 + l15; if (rowc > 65) rowc = 65;
                bf16x8 qh2[2], ql2[2];
#pragma unroll
                for (int ks = 0; ks < 2; ++ks) {
                    qh2[ks] = *(const bf16x8*)&lds[QH + rowc * 72 + ks * 32 + lg * 8];
                    ql2[ks] = *(const bf16x8*)&lds[QL + rowc * 72 + ks * 32 + lg * 8];
                }
                f32x4 c[5];
#pragma unroll
                for (int nt = 0; nt < 5; ++nt) {
                    f32x4 acc = {0,0,0,0};
                    int colr = nt * 16 + l15; if (colr > 65) colr = 65;
#pragma unroll
                    for (int ks = 0; ks < 2; ++ks) {
                        bf16x8 khf = *(const bf16x8*)&lds[KH + colr * 72 + ks * 32 + lg * 8];
                        bf16x8 klf = *(const bf16x8*)&lds[KL + colr * 72 + ks * 32 + lg * 8];
                        acc = __builtin_amdgcn_mfma_f32_16x16x32_bf16(qh2[ks], khf, acc, 0, 0, 0);
                        acc = __builtin_amdgcn_mfma_f32_16x16x32_bf16(qh2[ks], klf, acc, 0, 0, 0);
                        acc = __builtin_amdgcn_mfma_f32_16x16x32_bf16(ql2[ks], khf, acc, 0, 0, 0);
                    }
                    c[nt] = acc;
                }
#pragma unroll
                for (int r = 0; r < 4; ++r) {
                    int srow = mt * 16 + lg * 4 + r;
                    int fi = (srow >= 44) ? 2 : ((srow >= 22) ? 1 : 0);
                    float sv[5];
                    float mv = -INFINITY;
#pragma unroll
                    for (int nt = 0; nt < 5; ++nt) {
                        int j = nt * 16 + l15;
                        int fj = (j >= 44) ? 2 : ((j >= 22) ? 1 : 0);
                        float s = c[nt][r];
                        if ((fi == 0 && fj == 2) || (fi == 2 && fj == 0)) s = 0.f;
                        sv[nt] = s;
                        if (j < NS) mv = fmaxf(mv, s);
                    }
#pragma unroll
                    for (int off = 1; off < 16; off <<= 1) mv = fmaxf(mv, __shfl_xor(mv, off));
                    float thr = mv * (1.f / 9.f);
                    float ev[5];
                    float M2 = -INFINITY;
#pragma unroll
                    for (int nt = 0; nt < 5; ++nt) {
                        int j = nt * 16 + l15;
                        float e = (j < NS && fabsf(sv[nt]) > thr) ? sv[nt] : NEGV;
                        ev[nt] = e;
                        M2 = fmaxf(M2, e);
                    }
#pragma unroll
                    for (int off = 1; off < 16; off <<= 1) M2 = fmaxf(M2, __shfl_xor(M2, off));
                    float sum = 0.f;
#pragma unroll
                    for (int nt = 0; nt < 5; ++nt) {
                        float p = __expf(ev[nt] - M2);
                        pst[t][nt][r] = p;
                        sum += p;
                    }
#pragma unroll
                    for (int off = 1; off < 16; off <<= 1) sum += __shfl_xor(sum, off);
                    float inv = 1.f / sum;
#pragma unroll
                    for (int nt = 0; nt < 5; ++nt) pst[t][nt][r] *= inv;
                }
#pragma unroll
                for (int r = 0; r < 4; ++r) {
                    int srow = mt * 16 + lg * 4 + r;
                    if (srow < NS) {
#pragma unroll
                        for (int nt = 0; nt < 4; ++nt)
                            lds[QH + srow * 72 + nt * 16 + l15] = bfc(pst[t][nt][r]);
                        if (l15 < 2) lds[QH + srow * 72 + 64 + l15] = bfc(pst[t][4][r]);
                    }
                }
            }
        }
        __syncthreads();

#pragma unroll
        for (int t5 = 0; t5 < 5; ++t5) {
            int tile = wv * 5 + t5;
            int mt = tile >> 2, nt = tile & 3;
            int rowc = mt * 16 + l15; if (rowc > 65) rowc = 65;
            int dn = nt * 16 + l15;
            f32x4 acc = {0,0,0,0};
#pragma unroll
            for (int ks = 0; ks < 2; ++ks) {
                bf16x8 pa = *(const bf16x8*)&lds[QH + rowc * 72 + ks * 32 + lg * 8];
                bf16x8 vb = *(const bf16x8*)&lds[VT_F + dn * 72 + ks * 32 + lg * 8];
                acc = __builtin_amdgcn_mfma_f32_16x16x32_bf16(pa, vb, acc, 0, 0, 0);
            }
            float v64 = b2f(lds[VT_F + dn * 72 + 64]);
            float v65 = b2f(lds[VT_F + dn * 72 + 65]);
#pragma unroll
            for (int r = 0; r < 4; ++r) {
                int s2 = mt * 16 + lg * 4 + r;
                if (s2 < NS) {
                    float p64 = b2f(lds[QH + s2 * 72 + 64]);
                    float p65 = b2f(lds[QH + s2 * 72 + 65]);
                    OTf[dn * 76 + s2] = acc[r] + p64 * v64 + p65 * v65;
                }
            }
        }
        __syncthreads();

#pragma unroll
        for (int t = 0; t < 2; ++t) {
            f32x4 acc = {0,0,0,0};
            const int d2 = wv * 16 + l15;
#pragma unroll
            for (int ks = 0; ks < 2; ++ks) {
                f32x4 f0 = *(const f32x4*)&OTf[d2 * 76 + ks * 32 + lg * 8];
                f32x4 f1 = *(const f32x4*)&OTf[d2 * 76 + ks * 32 + lg * 8 + 4];
                bf16x8 bb;
#pragma unroll
                for (int i = 0; i < 4; ++i) {
                    bb[i]     = (short)bfc(f0[i]);
                    bb[i + 4] = (short)bfc(f1[i]);
                }
                acc = __builtin_amdgcn_mfma_f32_16x16x32_bf16(wfrag[t][ks], bb, acc, 0, 0, 0);
            }
            float o64 = OTf[d2 * 76 + 64];
            float o65 = OTf[d2 * 76 + 65];
#pragma unroll
            for (int r = 0; r < 4; ++r) {
                int jj = t * 16 + lg * 4 + r;
                if (jj < NJ) {
                    float res = acc[r] + Wcls[64 * NJ + jj] * o64
                                       + Wcls[65 * NJ + jj] * o65 + bcls[jj];
                    out[((b * (NW * NJ) + w * NJ + jj) * NHD) + h * 64 + wv * 16 + l15] = res;
                }
            }
        }
        __syncthreads();
    }
}

__global__ __launch_bounds__(256) void ft_ln_kernel(
    const float* __restrict__ Wft, const float* __restrict__ bft,
    const float* __restrict__ a2, const float* __restrict__ b2,
    float* __restrict__ out)
{
    __shared__ float sA[16 * NOUT];
    const int tid = threadIdx.x;
    const int base = blockIdx.x * (16 * NOUT);

    for (int idx = tid; idx < 16 * NOUT; idx += 256) sA[idx] = out[base + idx];
    __syncthreads();

    float a0[16], a1[16];
    const float bf0 = bft[tid], bf1 = bft[tid + 256];
#pragma unroll
    for (int r = 0; r < 16; ++r) { a0[r] = bf0; a1[r] = bf1; }

    for (int f = 0; f < NOUT; ++f) {
        float w0 = Wft[f * NOUT + tid];
        float w1 = Wft[f * NOUT + tid + 256];
#pragma unroll
        for (int r = 0; r < 16; ++r) {
            float a = sA[r * NOUT + f];
            a0[r] = fmaf(a, w0, a0[r]);
            a1[r] = fmaf(a, w1, a1[r]);
        }
    }
    __syncthreads();
#pragma unroll
    for (int r = 0; r < 16; ++r) {
        sA[r * NOUT + tid]       = fmaxf(a0[r], 0.f);
        sA[r * NOUT + tid + 256] = fmaxf(a1[r], 0.f);
    }
    __syncthreads();

    const int lane = tid & 63, wvv = tid >> 6;
    for (int r = wvv * 4; r < wvv * 4 + 4; ++r) {
        float s = 0.f, sq = 0.f;
        float vals[8];
#pragma unroll
        for (int u = 0; u < 8; ++u) {
            float y = sA[r * NOUT + u * 64 + lane];
            vals[u] = y;
            s += y;
            sq = fmaf(y, y, sq);
        }
#pragma unroll
        for (int off = 32; off; off >>= 1) {
            s  += __shfl_xor(s,  off);
            sq += __shfl_xor(sq, off);
        }
        float mean = s * (1.0f / 512.0f);
        float var  = fmaxf((sq - 512.0f * mean * mean) * (1.0f / 511.0f), 0.0f);
        float inv  = 1.0f / (sqrtf(var) + 1e-6f);
#pragma unroll
        for (int u = 0; u < 8; ++u) {
            int c = u * 64 + lane;
            out[base + r * NOUT + c] = a2[c] * (vals[u] - mean) * inv + b2[c];
        }
    }
}

extern "C" void kernel_launch(void* const* d_in, const int* in_sizes, int n_in,
                              void* d_out, int out_size, void* d_ws, size_t ws_size,
                              hipStream_t stream) {
    (void)in_sizes; (void)n_in; (void)out_size;
    const float* x    = (const float*)d_in[0];
    const float* Wq   = (const float*)d_in[1];
    const float* bq   = (const float*)d_in[2];
    const float* Wk   = (const float*)d_in[3];
    const float* bk   = (const float*)d_in[4];
    const float* Wv   = (const float*)d_in[5];
    const float* bv   = (const float*)d_in[6];
    const float* Wcls = (const float*)d_in[7];
    const float* bcls = (const float*)d_in[8];
    const float* Wft  = (const float*)d_in[9];
    const float* bft  = (const float*)d_in[10];
    const float* a2   = (const float*)d_in[11];
    const float* b2   = (const float*)d_in[12];
    float* out = (float*)d_out;

    if (ws_size >= WS_FULL_BYTES) {
        unsigned short* ws = (unsigned short*)d_ws;
        prep_kernel<<<1880, 256, 0, stream>>>(Wq, Wk, Wv, Wft, ws);
        qkv_kernel<<<1056, 256, 0, stream>>>(x, bq, bk, bv, ws, ws);
        attn_kernel12<<<(NB * NW * NH) / 4, 256, 0, stream>>>(ws, Wcls, bcls, out);
        ft_ln4<<<528, 256, 0, stream>>>(ws, bft, a2, b2, out);
    } else {
        attn_kernel<<<NB * NW * 2, 256, 0, stream>>>(x, Wq, bq, Wk, bk, Wv, bv,
                                                     Wcls, bcls, out);
        ft_ln_kernel<<<(NB * NW * NJ) / 16, 256, 0, stream>>>(Wft, bft, a2, b2, out);
    }
}